// Round 3
// baseline (4563.765 us; speedup 1.0000x reference)
//
#include <hip/hip_runtime.h>
#include <hip/hip_bf16.h>

#define N_USER 50000
#define N_ITEM 30000
#define NTOT   80000
#define EMB    64
#define FAC    4
#define DSUB   16
#define EDGES  1000000

// ws layout (floats):
//   ego  : +0          NTOT*EMB  = 5,120,000
//   fac  : +5,120,000  NTOT*EMB  = 5,120,000
//   sum  : +10,240,000 NTOT*EMB  = 5,120,000
//   A    : +15,360,000 EDGES*FAC = 4,000,000
//   nA   : +19,360,000 EDGES*FAC = 4,000,000
//   dv   : +23,360,000 NTOT*FAC  =   320,000
//   flag : +23,680,000 (1 int)
// total ~94.7 MB

// Detect whether the raw embedding buffer is fp32 (read-as-bf16 would show
// inf/NaN bit patterns among the low halves) or genuine bf16 (no such patterns).
// Round-1/2 evidence says fp32; this keeps the kernel robust either way.
__global__ void k_detect(const unsigned short* __restrict__ raw, int* __restrict__ flag) {
    __shared__ int s;
    if (threadIdx.x == 0) s = 0;
    __syncthreads();
    int c = 0;
    for (int i = threadIdx.x; i < 16384; i += 256) {
        unsigned short u = raw[i];
        if ((u & 0x7F80) == 0x7F80) c++;   // bf16 inf/NaN pattern
    }
    atomicAdd(&s, c);
    __syncthreads();
    if (threadIdx.x == 0) *flag = (s > 0) ? 1 : 0;  // 1 => buffer is fp32
}

__global__ void k_init(const void* __restrict__ ue, const void* __restrict__ ie,
                       const int* __restrict__ flag,
                       float* __restrict__ ego, float* __restrict__ sum) {
    int i = blockIdx.x * blockDim.x + threadIdx.x;
    if (i >= NTOT * EMB) return;
    bool isf32 = (*flag != 0);
    float v;
    if (i < N_USER * EMB) {
        v = isf32 ? ((const float*)ue)[i]
                  : __bfloat162float(((const __hip_bfloat16*)ue)[i]);
    } else {
        int j = i - N_USER * EMB;
        v = isf32 ? ((const float*)ie)[j]
                  : __bfloat162float(((const __hip_bfloat16*)ie)[j]);
    }
    ego[i] = v;
    sum[i] = v;
}

__global__ void k_initA(float* __restrict__ A) {
    int i = blockIdx.x * blockDim.x + threadIdx.x;
    if (i < EDGES * FAC) A[i] = 1.0f;
}

// softmax over the 4 factors of A, store normA, scatter-add into dval[h]
__global__ void k_edge_pre(const float* __restrict__ A, const int* __restrict__ h,
                           float* __restrict__ nA, float* __restrict__ dv) {
    int e = blockIdx.x * blockDim.x + threadIdx.x;
    if (e >= EDGES) return;
    float4 a = ((const float4*)A)[e];
    float m = fmaxf(fmaxf(a.x, a.y), fmaxf(a.z, a.w));
    float e0 = __expf(a.x - m), e1 = __expf(a.y - m),
          e2 = __expf(a.z - m), e3 = __expf(a.w - m);
    float inv = 1.0f / (e0 + e1 + e2 + e3);
    float4 n = make_float4(e0 * inv, e1 * inv, e2 * inv, e3 * inv);
    ((float4*)nA)[e] = n;
    int hh = h[e] * FAC;
    unsafeAtomicAdd(&dv[hh + 0], n.x);
    unsafeAtomicAdd(&dv[hh + 1], n.y);
    unsafeAtomicAdd(&dv[hh + 2], n.z);
    unsafeAtomicAdd(&dv[hh + 3], n.w);
}

// dv -> 1/sqrt(clip(dv, 1e-8)) in place
__global__ void k_dinv(float* __restrict__ dv) {
    int i = blockIdx.x * blockDim.x + threadIdx.x;
    if (i < NTOT * FAC) dv[i] = rsqrtf(fmaxf(dv[i], 1e-8f));
}

// message passing: 16 threads per edge, each thread does one float4 slice
__global__ void k_mp(const float* __restrict__ ego, const float* __restrict__ nA,
                     const float* __restrict__ dv, const int* __restrict__ h,
                     const int* __restrict__ t, float* __restrict__ fac) {
    int tid = blockIdx.x * blockDim.x + threadIdx.x;
    if (tid >= EDGES * 16) return;
    int e = tid >> 4;
    int lane = tid & 15;
    int f = lane >> 2;   // factor 0..3
    int q = lane & 3;    // float4 slice within factor
    int hh = h[e];
    int tt = t[e];
    float w = nA[e * 4 + f] * dv[hh * 4 + f] * dv[tt * 4 + f];
    float4 v = ((const float4*)(ego + tt * 64))[f * 4 + q];
    float* dst = fac + hh * 64 + f * 16 + q * 4;
    unsafeAtomicAdd(dst + 0, v.x * w);
    unsafeAtomicAdd(dst + 1, v.y * w);
    unsafeAtomicAdd(dst + 2, v.z * w);
    unsafeAtomicAdd(dst + 3, v.w * w);
}

// dynamic routing update: 1 thread per (edge, factor)
__global__ void k_aupd(const float* __restrict__ ego, const float* __restrict__ fac,
                       const int* __restrict__ h, const int* __restrict__ t,
                       float* __restrict__ A) {
    int tid = blockIdx.x * blockDim.x + threadIdx.x;
    if (tid >= EDGES * FAC) return;
    int e = tid >> 2;
    int f = tid & 3;
    int hh = h[e];
    int tt = t[e];
    const float4* hp = (const float4*)(fac + hh * 64 + f * 16);
    const float4* tp = (const float4*)(ego + tt * 64 + f * 16);
    float hv[16], tv[16];
#pragma unroll
    for (int i = 0; i < 4; ++i) {
        float4 a = hp[i];
        hv[4 * i + 0] = a.x; hv[4 * i + 1] = a.y; hv[4 * i + 2] = a.z; hv[4 * i + 3] = a.w;
        float4 b = tp[i];
        tv[4 * i + 0] = b.x; tv[4 * i + 1] = b.y; tv[4 * i + 2] = b.z; tv[4 * i + 3] = b.w;
    }
    float hn2 = 0.f, tn2 = 0.f;
#pragma unroll
    for (int i = 0; i < 16; ++i) { hn2 += hv[i] * hv[i]; tn2 += tv[i] * tv[i]; }
    float rh = 1.0f / fmaxf(sqrtf(hn2), 1e-12f);
    float rt = 1.0f / fmaxf(sqrtf(tn2), 1e-12f);
    float s = 0.f;
#pragma unroll
    for (int i = 0; i < 16; ++i) s += hv[i] * tanhf(tv[i] * rt);
    A[e * 4 + f] += s * rh;
}

__global__ void k_addsum(float* __restrict__ sum, const float* __restrict__ fac) {
    int i = blockIdx.x * blockDim.x + threadIdx.x;
    if (i < NTOT * EMB) sum[i] += fac[i];
}

// Output is fp32 (reference returns jnp.float32; round-2 evidence confirms).
__global__ void k_final(const float* __restrict__ sum, float* __restrict__ out) {
    int i = blockIdx.x * blockDim.x + threadIdx.x;
    if (i < NTOT * EMB) out[i] = sum[i] * (1.0f / 3.0f);
}

extern "C" void kernel_launch(void* const* d_in, const int* in_sizes, int n_in,
                              void* d_out, int out_size, void* d_ws, size_t ws_size,
                              hipStream_t stream) {
    const void* ue = d_in[0];
    const void* ie = d_in[1];
    const int* hl = (const int*)d_in[2];
    const int* tl = (const int*)d_in[3];
    float* out = (float*)d_out;

    float* ws  = (float*)d_ws;
    float* ego = ws;
    float* fac = ws + 5120000;
    float* sum = ws + 10240000;
    float* A   = ws + 15360000;
    float* nA  = ws + 19360000;
    float* dv  = ws + 23360000;
    int* flag  = (int*)(ws + 23680000);

    k_detect<<<1, 256, 0, stream>>>((const unsigned short*)ue, flag);
    k_init<<<(NTOT * EMB + 255) / 256, 256, 0, stream>>>(ue, ie, flag, ego, sum);
    k_initA<<<(EDGES * FAC + 255) / 256, 256, 0, stream>>>(A);

    for (int layer = 0; layer < 2; ++layer) {
        for (int it = 0; it < 2; ++it) {
            hipMemsetAsync(dv, 0, NTOT * FAC * sizeof(float), stream);
            k_edge_pre<<<(EDGES + 255) / 256, 256, 0, stream>>>(A, hl, nA, dv);
            k_dinv<<<(NTOT * FAC + 255) / 256, 256, 0, stream>>>(dv);
            hipMemsetAsync(fac, 0, NTOT * EMB * sizeof(float), stream);
            k_mp<<<(EDGES * 16 + 255) / 256, 256, 0, stream>>>(ego, nA, dv, hl, tl, fac);
            if (!(layer == 1 && it == 1))
                k_aupd<<<(EDGES * FAC + 255) / 256, 256, 0, stream>>>(ego, fac, hl, tl, A);
        }
        k_addsum<<<(NTOT * EMB + 255) / 256, 256, 0, stream>>>(sum, fac);
        float* tmp = ego; ego = fac; fac = tmp;
    }
    k_final<<<(NTOT * EMB + 255) / 256, 256, 0, stream>>>(sum, out);
}

// Round 4
// 1177.498 us; speedup vs baseline: 3.8758x; 3.8758x over previous
//
#include <hip/hip_runtime.h>
#include <hip/hip_bf16.h>

#define N_USER 50000
#define N_ITEM 30000
#define NTOT   80000
#define EMB    64
#define FAC    4
#define DSUB   16
#define EDGES  1000000

// ws layout (float idx):
//   ego   : +0           5,120,000
//   fac   : +5,120,000   5,120,000
//   tnh   : +10,240,000  5,120,000
//   A     : +15,360,000  4,000,000
//   dvinv : +19,360,000    320,000
//   rhn   : +19,680,000    320,000
//   flag  : +20,000,000  (1 int)
//   ints  : +20,000,064  deg 80000 | off 80001 | cur 80000 | et 2*1,000,000
// total ~89 MB

// ---- input dtype detector (fp32 read-as-bf16 shows inf/NaN bit patterns) ----
__global__ void k_detect(const unsigned short* __restrict__ raw, int* __restrict__ flag) {
    __shared__ int s;
    if (threadIdx.x == 0) s = 0;
    __syncthreads();
    int c = 0;
    for (int i = threadIdx.x; i < 16384; i += 256) {
        unsigned short u = raw[i];
        if ((u & 0x7F80) == 0x7F80) c++;
    }
    atomicAdd(&s, c);
    __syncthreads();
    if (threadIdx.x == 0) *flag = (s > 0) ? 1 : 0;  // 1 => fp32
}

__global__ void k_init(const void* __restrict__ ue, const void* __restrict__ ie,
                       const int* __restrict__ flag,
                       float* __restrict__ ego, float* __restrict__ out) {
    int i = blockIdx.x * blockDim.x + threadIdx.x;
    if (i >= NTOT * EMB) return;
    bool isf32 = (*flag != 0);
    float v;
    if (i < N_USER * EMB) {
        v = isf32 ? ((const float*)ue)[i]
                  : __bfloat162float(((const __hip_bfloat16*)ue)[i]);
    } else {
        int j = i - N_USER * EMB;
        v = isf32 ? ((const float*)ie)[j]
                  : __bfloat162float(((const __hip_bfloat16*)ie)[j]);
    }
    ego[i] = v;
    out[i] = v * (1.0f / 3.0f);   // mean-of-3 accumulator, term 1
}

__global__ void k_initA(float* __restrict__ A) {
    int i = blockIdx.x * blockDim.x + threadIdx.x;
    if (i < EDGES * FAC) A[i] = 1.0f;
}

// ---- CSR build ----
__global__ void k_deg(const int* __restrict__ h, int* __restrict__ deg) {
    int e = blockIdx.x * blockDim.x + threadIdx.x;
    if (e < EDGES) atomicAdd(&deg[h[e]], 1);
}

#define SCAN_B 1024
__global__ void k_scan(const int* __restrict__ deg, int* __restrict__ off, int* __restrict__ cur) {
    __shared__ int buf[SCAN_B];
    __shared__ int carry;
    if (threadIdx.x == 0) carry = 0;
    __syncthreads();
    for (int base = 0; base < NTOT; base += SCAN_B) {
        int i = base + threadIdx.x;
        int v = (i < NTOT) ? deg[i] : 0;
        buf[threadIdx.x] = v;
        __syncthreads();
        for (int s = 1; s < SCAN_B; s <<= 1) {
            int t = (threadIdx.x >= s) ? buf[threadIdx.x - s] : 0;
            __syncthreads();
            buf[threadIdx.x] += t;
            __syncthreads();
        }
        int excl = carry + buf[threadIdx.x] - v;
        if (i < NTOT) { off[i] = excl; cur[i] = excl; }
        __syncthreads();
        if (threadIdx.x == SCAN_B - 1) carry += buf[SCAN_B - 1];
        __syncthreads();
    }
    if (threadIdx.x == 0) off[NTOT] = carry;
}

__global__ void k_scatter(const int* __restrict__ h, const int* __restrict__ t,
                          int* __restrict__ cur, int2* __restrict__ et) {
    int e = blockIdx.x * blockDim.x + threadIdx.x;
    if (e >= EDGES) return;
    int pos = atomicAdd(&cur[h[e]], 1);
    et[pos] = make_int2(e, t[e]);
}

// ---- per-layer: tnh[n] = tanh(ego[n] normalized per 16-dim factor) ----
__global__ void k_tnh(const float* __restrict__ ego, float* __restrict__ tnh) {
    int gid = blockIdx.x * blockDim.x + threadIdx.x;
    int wid = gid >> 6;
    int lane = threadIdx.x & 63;
    if (wid >= NTOT) return;
    float v = ego[wid * 64 + lane];
    float ss = v * v;
    ss += __shfl_xor(ss, 1); ss += __shfl_xor(ss, 2);
    ss += __shfl_xor(ss, 4); ss += __shfl_xor(ss, 8);
    float r = 1.0f / fmaxf(sqrtf(ss), 1e-12f);
    tnh[wid * 64 + lane] = tanhf(v * r);
}

// ---- pass 0 dinv: softmax(ones)=0.25 -> dval = 0.25*deg ----
__global__ void k_dinv0(const int* __restrict__ deg, float* __restrict__ dvinv) {
    int i = blockIdx.x * blockDim.x + threadIdx.x;
    if (i >= NTOT * FAC) return;
    float dval = 0.25f * (float)deg[i >> 2];
    dvinv[i] = rsqrtf(fmaxf(dval, 1e-8f));
}

// ---- later passes: dval[n] = sum over incident edges of softmax(A[e]) ----
__global__ void k_dv(const float* __restrict__ A, const int* __restrict__ off,
                     const int2* __restrict__ et, float* __restrict__ dvinv) {
    int n = blockIdx.x * blockDim.x + threadIdx.x;
    if (n >= NTOT) return;
    int beg = off[n], end = off[n + 1];
    float s0 = 0.f, s1 = 0.f, s2 = 0.f, s3 = 0.f;
    for (int j = beg; j < end; ++j) {
        int e = et[j].x;
        float4 a = ((const float4*)A)[e];
        float m = fmaxf(fmaxf(a.x, a.y), fmaxf(a.z, a.w));
        float e0 = __expf(a.x - m), e1 = __expf(a.y - m),
              e2 = __expf(a.z - m), e3 = __expf(a.w - m);
        float inv = 1.0f / (e0 + e1 + e2 + e3);
        s0 += e0 * inv; s1 += e1 * inv; s2 += e2 * inv; s3 += e3 * inv;
    }
    float4 r;
    r.x = rsqrtf(fmaxf(s0, 1e-8f));
    r.y = rsqrtf(fmaxf(s1, 1e-8f));
    r.z = rsqrtf(fmaxf(s2, 1e-8f));
    r.w = rsqrtf(fmaxf(s3, 1e-8f));
    ((float4*)dvinv)[n] = r;
}

// ---- message passing, gather form: one wave per head node, lane = dim ----
__global__ void k_mp(const float* __restrict__ ego, const float* __restrict__ A,
                     const float* __restrict__ dvinv, const int* __restrict__ off,
                     const int2* __restrict__ et,
                     float* __restrict__ fac, float* __restrict__ rhn,
                     float* __restrict__ out, int writeRhn, int addOut) {
    int gid = blockIdx.x * blockDim.x + threadIdx.x;
    int wid = gid >> 6;
    int lane = threadIdx.x & 63;
    if (wid >= NTOT) return;
    int f = lane >> 4;
    int beg = off[wid], end = off[wid + 1];
    float dvh = dvinv[wid * 4 + f];
    float acc = 0.f;
    for (int j = beg; j < end; ++j) {
        int2 p = et[j];
        int e = p.x, t = p.y;
        float4 a = ((const float4*)A)[e];
        float m = fmaxf(fmaxf(a.x, a.y), fmaxf(a.z, a.w));
        float e0 = __expf(a.x - m), e1 = __expf(a.y - m),
              e2 = __expf(a.z - m), e3 = __expf(a.w - m);
        float inv = 1.0f / (e0 + e1 + e2 + e3);
        float nf = (f == 0) ? e0 : (f == 1) ? e1 : (f == 2) ? e2 : e3;
        float w = nf * inv * dvh * dvinv[t * 4 + f];
        acc += w * ego[t * 64 + lane];
    }
    fac[wid * 64 + lane] = acc;
    if (addOut) out[wid * 64 + lane] += acc * (1.0f / 3.0f);
    if (writeRhn) {
        float ss = acc * acc;
        ss += __shfl_xor(ss, 1); ss += __shfl_xor(ss, 2);
        ss += __shfl_xor(ss, 4); ss += __shfl_xor(ss, 8);
        if ((lane & 15) == 0) rhn[wid * 4 + f] = 1.0f / fmaxf(sqrtf(ss), 1e-12f);
    }
}

// ---- routing update: A[e,f] += rhn[h,f] * dot(fac[h,f,:], tnh[t,f,:]) ----
__global__ void k_aupd(const float* __restrict__ fac, const float* __restrict__ tnh,
                       const int* __restrict__ hl, const int* __restrict__ tl,
                       const float* __restrict__ rhn, float* __restrict__ A) {
    int tid = blockIdx.x * blockDim.x + threadIdx.x;
    if (tid >= EDGES * FAC) return;
    int e = tid >> 2, f = tid & 3;
    int h = hl[e], t = tl[e];
    const float4* hp = (const float4*)(fac + h * 64 + f * 16);
    const float4* tp = (const float4*)(tnh + t * 64 + f * 16);
    float s = 0.f;
#pragma unroll
    for (int i = 0; i < 4; ++i) {
        float4 a = hp[i];
        float4 b = tp[i];
        s += a.x * b.x + a.y * b.y + a.z * b.z + a.w * b.w;
    }
    A[tid] += s * rhn[h * 4 + f];
}

extern "C" void kernel_launch(void* const* d_in, const int* in_sizes, int n_in,
                              void* d_out, int out_size, void* d_ws, size_t ws_size,
                              hipStream_t stream) {
    const void* ue = d_in[0];
    const void* ie = d_in[1];
    const int* hl = (const int*)d_in[2];
    const int* tl = (const int*)d_in[3];
    float* out = (float*)d_out;

    float* ws    = (float*)d_ws;
    float* ego   = ws;
    float* fac   = ws + 5120000;
    float* tnh   = ws + 10240000;
    float* A     = ws + 15360000;
    float* dvinv = ws + 19360000;
    float* rhn   = ws + 19680000;
    int*   flag  = (int*)(ws + 20000000);
    int*   ibase = (int*)(ws + 20000064);
    int*   deg   = ibase;                 // 80000
    int*   off   = ibase + 80000;         // 80001
    int*   cur   = ibase + 160001;        // 80000
    int2*  et    = (int2*)(ibase + 240004); // 1,000,000 int2 (8B-aligned: 240004 even)

    k_detect<<<1, 256, 0, stream>>>((const unsigned short*)ue, flag);
    k_init<<<20000, 256, 0, stream>>>(ue, ie, flag, ego, out);
    k_initA<<<15625, 256, 0, stream>>>(A);

    hipMemsetAsync(deg, 0, NTOT * sizeof(int), stream);
    k_deg<<<3907, 256, 0, stream>>>(hl, deg);
    k_scan<<<1, SCAN_B, 0, stream>>>(deg, off, cur);
    k_scatter<<<3907, 256, 0, stream>>>(hl, tl, cur, et);

    for (int layer = 0; layer < 2; ++layer) {
        k_tnh<<<20000, 256, 0, stream>>>(ego, tnh);
        for (int it = 0; it < 2; ++it) {
            int pass = layer * 2 + it;
            if (pass == 0)
                k_dinv0<<<1250, 256, 0, stream>>>(deg, dvinv);
            else
                k_dv<<<313, 256, 0, stream>>>(A, off, et, dvinv);
            int last = (pass == 3);
            int addOut = (it == 1);
            k_mp<<<20000, 256, 0, stream>>>(ego, A, dvinv, off, et,
                                            fac, rhn, out, !last, addOut);
            if (!last)
                k_aupd<<<15625, 256, 0, stream>>>(fac, tnh, hl, tl, rhn, A);
        }
        float* tmp = ego; ego = fac; fac = tmp;
    }
}

// Round 5
// 1167.377 us; speedup vs baseline: 3.9094x; 1.0087x over previous
//
#include <hip/hip_runtime.h>
#include <hip/hip_bf16.h>

#define N_USER 50000
#define N_ITEM 30000
#define NTOT   80000
#define EMB    64
#define FAC    4
#define EDGES  1000000
#define LOG4   1.3862943611198906f
#define SB     1024
#define NBLK   79   // ceil(80000/1024)

// ws layout (float idx):
//   ego   +0           5,120,000
//   fac   +5,120,000   5,120,000
//   tnh   +10,240,000  5,120,000
//   L     +15,360,000  4,000,000   (log-softmax of A, CSR position order)
//   dvinv +19,360,000    320,000
//   rhn   +19,680,000    320,000
//   flag  +20,000,000    16
//   ints  +20,000,016: deg 80000 | off 80001 | cur 80000 | tlist 1,000,000 | bsum 128 | bbase 128
// total ~85 MB

// ---- input dtype detector (fp32 read-as-bf16 shows inf/NaN bit patterns) ----
__global__ void k_detect(const unsigned short* __restrict__ raw, int* __restrict__ flag) {
    __shared__ int s;
    if (threadIdx.x == 0) s = 0;
    __syncthreads();
    int c = 0;
    for (int i = threadIdx.x; i < 16384; i += 256) {
        unsigned short u = raw[i];
        if ((u & 0x7F80) == 0x7F80) c++;
    }
    atomicAdd(&s, c);
    __syncthreads();
    if (threadIdx.x == 0) *flag = (s > 0) ? 1 : 0;  // 1 => fp32
}

__global__ void k_init(const void* __restrict__ ue, const void* __restrict__ ie,
                       const int* __restrict__ flag,
                       float* __restrict__ ego, float* __restrict__ out) {
    int i = blockIdx.x * blockDim.x + threadIdx.x;
    if (i >= NTOT * EMB) return;
    bool isf32 = (*flag != 0);
    float v;
    if (i < N_USER * EMB) {
        v = isf32 ? ((const float*)ue)[i]
                  : __bfloat162float(((const __hip_bfloat16*)ue)[i]);
    } else {
        int j = i - N_USER * EMB;
        v = isf32 ? ((const float*)ie)[j]
                  : __bfloat162float(((const __hip_bfloat16*)ie)[j]);
    }
    ego[i] = v;
    out[i] = v * (1.0f / 3.0f);   // mean-of-3 accumulator, term 1
}

// ---- CSR build ----
__global__ void k_deg(const int* __restrict__ h, int* __restrict__ deg) {
    int e = blockIdx.x * blockDim.x + threadIdx.x;
    if (e < EDGES) atomicAdd(&deg[h[e]], 1);
}

__global__ void k_scan1(const int* __restrict__ deg, int* __restrict__ off,
                        int* __restrict__ bsum) {
    __shared__ int buf[SB];
    int tid = threadIdx.x;
    int i = blockIdx.x * SB + tid;
    int v = (i < NTOT) ? deg[i] : 0;
    buf[tid] = v;
    __syncthreads();
    for (int s = 1; s < SB; s <<= 1) {
        int t = (tid >= s) ? buf[tid - s] : 0;
        __syncthreads();
        buf[tid] += t;
        __syncthreads();
    }
    if (i < NTOT) off[i] = buf[tid] - v;          // block-local exclusive
    if (tid == SB - 1) bsum[blockIdx.x] = buf[tid];
}

__global__ void k_scan2(const int* __restrict__ bsum, int* __restrict__ bbase) {
    __shared__ int b[128];
    int tid = threadIdx.x;
    int v = (tid < NBLK) ? bsum[tid] : 0;
    b[tid] = v;
    __syncthreads();
    for (int s = 1; s < 128; s <<= 1) {
        int t = (tid >= s) ? b[tid - s] : 0;
        __syncthreads();
        b[tid] += t;
        __syncthreads();
    }
    if (tid < NBLK) bbase[tid] = b[tid] - v;      // exclusive base per block
}

__global__ void k_scan3(int* __restrict__ off, const int* __restrict__ bbase,
                        int* __restrict__ cur) {
    int i = blockIdx.x * blockDim.x + threadIdx.x;
    if (i < NTOT) {
        int o = off[i] + bbase[i >> 10];
        off[i] = o;
        cur[i] = o;
    }
    if (i == 0) off[NTOT] = EDGES;
}

__global__ void k_scatter(const int* __restrict__ h, const int* __restrict__ t,
                          int* __restrict__ cur, int* __restrict__ tlist) {
    int e = blockIdx.x * blockDim.x + threadIdx.x;
    if (e >= EDGES) return;
    int pos = atomicAdd(&cur[h[e]], 1);
    tlist[pos] = t[e];
}

// ---- per-layer: tnh[n] = tanh(ego[n] normalized per 16-dim factor) ----
__global__ void k_tnh(const float* __restrict__ ego, float* __restrict__ tnh) {
    int gid = blockIdx.x * blockDim.x + threadIdx.x;
    int wid = gid >> 6;
    int lane = threadIdx.x & 63;
    if (wid >= NTOT) return;
    float v = ego[wid * 64 + lane];
    float ss = v * v;
    ss += __shfl_xor(ss, 1); ss += __shfl_xor(ss, 2);
    ss += __shfl_xor(ss, 4); ss += __shfl_xor(ss, 8);
    float r = 1.0f / fmaxf(sqrtf(ss), 1e-12f);
    tnh[wid * 64 + lane] = tanhf(v * r);
}

// ---- pass 0 dinv: softmax(ones)=0.25 -> dval = 0.25*deg ----
__global__ void k_dinv0(const int* __restrict__ deg, float* __restrict__ dvinv) {
    int i = blockIdx.x * blockDim.x + threadIdx.x;
    if (i >= NTOT * FAC) return;
    float dval = 0.25f * (float)deg[i >> 2];
    dvinv[i] = rsqrtf(fmaxf(dval, 1e-8f));
}

// ---- message passing, gather form: one wave per head node, lane = dim ----
// weight = exp(L[j,f]) * dvinv[h,f] * dvinv[t,f]   (pass0: 0.25 instead of exp)
__global__ void k_mp(const float* __restrict__ ego, const float* __restrict__ L,
                     const float* __restrict__ dvinv, const int* __restrict__ off,
                     const int* __restrict__ tlist,
                     float* __restrict__ fac, float* __restrict__ rhn,
                     float* __restrict__ out, int useL, int writeRhn, int addOut) {
    int gid = blockIdx.x * blockDim.x + threadIdx.x;
    int wid = gid >> 6;
    int lane = threadIdx.x & 63;
    if (wid >= NTOT) return;
    int f = lane >> 4;
    int beg = off[wid], end = off[wid + 1];
    float dvh = dvinv[wid * 4 + f];
    float acc = 0.f;
    for (int j = beg; j < end; ++j) {
        int t = tlist[j];
        float w = useL ? __expf(L[j * 4 + f]) : 0.25f;
        w *= dvh * dvinv[t * 4 + f];
        acc += w * ego[t * 64 + lane];
    }
    fac[wid * 64 + lane] = acc;
    if (addOut) out[wid * 64 + lane] += acc * (1.0f / 3.0f);
    if (writeRhn) {
        float ss = acc * acc;
        ss += __shfl_xor(ss, 1); ss += __shfl_xor(ss, 2);
        ss += __shfl_xor(ss, 4); ss += __shfl_xor(ss, 8);
        if ((lane & 15) == 0) rhn[wid * 4 + f] = 1.0f / fmaxf(sqrtf(ss), 1e-12f);
    }
}

// ---- fused routing update + next-pass degree:
//   per node n (one wave), fac[n] held in regs:
//     for each CSR position j: s = dot(fac[n,f,:], tnh[t,f,:])
//       y = L_old + rhn[n,f]*s  (L_old = -log4 on first pass)
//       L_new = y - logsumexp_f(y)   (stored; softmax-equivalent)
//       dval[n,f] += exp(L_new)
//   writes dvinv for the NEXT pass.
__global__ void k_fused(const float* __restrict__ fac, const float* __restrict__ tnh,
                        const float* __restrict__ rhn, const int* __restrict__ off,
                        const int* __restrict__ tlist,
                        float* __restrict__ L, float* __restrict__ dvinv, int first) {
    int gid = blockIdx.x * blockDim.x + threadIdx.x;
    int wid = gid >> 6;
    int lane = threadIdx.x & 63;
    if (wid >= NTOT) return;
    int f = lane >> 4;
    int beg = off[wid], end = off[wid + 1];
    float fv = fac[wid * 64 + lane];
    float rh = rhn[wid * 4 + f];
    float dval = 0.f;
    for (int j = beg; j < end; ++j) {
        int t = tlist[j];
        float tv = tnh[t * 64 + lane];
        float d = fv * tv;
        d += __shfl_xor(d, 1); d += __shfl_xor(d, 2);
        d += __shfl_xor(d, 4); d += __shfl_xor(d, 8);
        // all 16 lanes of factor group hold s = dot
        float y = (first ? -LOG4 : L[j * 4 + f]) + rh * d;
        float m = y;
        m = fmaxf(m, __shfl_xor(m, 16));
        m = fmaxf(m, __shfl_xor(m, 32));
        float ex = __expf(y - m);
        float sum = ex;
        sum += __shfl_xor(sum, 16);
        sum += __shfl_xor(sum, 32);
        if ((lane & 15) == 0) L[j * 4 + f] = y - m - __logf(sum);
        dval += ex / sum;   // softmax value for factor f
    }
    if ((lane & 15) == 0) dvinv[wid * 4 + f] = rsqrtf(fmaxf(dval, 1e-8f));
}

extern "C" void kernel_launch(void* const* d_in, const int* in_sizes, int n_in,
                              void* d_out, int out_size, void* d_ws, size_t ws_size,
                              hipStream_t stream) {
    const void* ue = d_in[0];
    const void* ie = d_in[1];
    const int* hl = (const int*)d_in[2];
    const int* tl = (const int*)d_in[3];
    float* out = (float*)d_out;

    float* ws    = (float*)d_ws;
    float* ego   = ws;
    float* fac   = ws + 5120000;
    float* tnh   = ws + 10240000;
    float* L     = ws + 15360000;
    float* dvinv = ws + 19360000;
    float* rhn   = ws + 19680000;
    int*   flag  = (int*)(ws + 20000000);
    int*   ib    = (int*)(ws + 20000016);
    int*   deg   = ib;                   // 80000
    int*   off   = ib + 80000;           // 80001
    int*   cur   = ib + 160001;          // 80000
    int*   tlist = ib + 240001;          // 1,000,000
    int*   bsum  = ib + 1240001;         // 128
    int*   bbase = ib + 1240129;         // 128

    k_detect<<<1, 256, 0, stream>>>((const unsigned short*)ue, flag);
    k_init<<<20000, 256, 0, stream>>>(ue, ie, flag, ego, out);

    hipMemsetAsync(deg, 0, NTOT * sizeof(int), stream);
    k_deg<<<3907, 256, 0, stream>>>(hl, deg);
    k_scan1<<<NBLK, SB, 0, stream>>>(deg, off, bsum);
    k_scan2<<<1, 128, 0, stream>>>(bsum, bbase);
    k_scan3<<<313, 256, 0, stream>>>(off, bbase, cur);
    k_scatter<<<3907, 256, 0, stream>>>(hl, tl, cur, tlist);

    // layer 0
    k_tnh<<<20000, 256, 0, stream>>>(ego, tnh);
    k_dinv0<<<1250, 256, 0, stream>>>(deg, dvinv);
    k_mp<<<20000, 256, 0, stream>>>(ego, L, dvinv, off, tlist, fac, rhn, out, 0, 1, 0); // pass0
    k_fused<<<20000, 256, 0, stream>>>(fac, tnh, rhn, off, tlist, L, dvinv, 1);
    k_mp<<<20000, 256, 0, stream>>>(ego, L, dvinv, off, tlist, fac, rhn, out, 1, 1, 1); // pass1
    k_fused<<<20000, 256, 0, stream>>>(fac, tnh, rhn, off, tlist, L, dvinv, 0);
    // layer 1
    { float* tmp = ego; ego = fac; fac = tmp; }
    k_tnh<<<20000, 256, 0, stream>>>(ego, tnh);
    k_mp<<<20000, 256, 0, stream>>>(ego, L, dvinv, off, tlist, fac, rhn, out, 1, 1, 0); // pass2
    k_fused<<<20000, 256, 0, stream>>>(fac, tnh, rhn, off, tlist, L, dvinv, 0);
    k_mp<<<20000, 256, 0, stream>>>(ego, L, dvinv, off, tlist, fac, rhn, out, 1, 0, 1); // pass3
}

// Round 6
// 653.377 us; speedup vs baseline: 6.9849x; 1.7867x over previous
//
#include <hip/hip_runtime.h>
#include <hip/hip_bf16.h>

#define N_USER 50000
#define N_ITEM 30000
#define NTOT   80000
#define EMB    64
#define FAC    4
#define EDGES  1000000
#define LOG4   1.3862943611198906f
#define SB     1024
#define NBLK   79   // ceil(80000/1024)

// ws layout (float idx):
//   ego   +0           5,120,000
//   fac   +5,120,000   5,120,000
//   tnh   +10,240,000  5,120,000
//   L     +15,360,000  4,000,000   (log-softmax of A, CSR position order)
//   dvinv +19,360,000    320,000
//   rhn   +19,680,000    320,000
//   flag  +20,000,000    16
//   ints  +20,000,016: deg 80000 | off 80001 | cur 80000 | tlist 1e6 | hlist 1e6 | bsum 128 | bbase 128
// total ~89 MB

// ---- input dtype detector (fp32 read-as-bf16 shows inf/NaN bit patterns) ----
__global__ void k_detect(const unsigned short* __restrict__ raw, int* __restrict__ flag) {
    __shared__ int s;
    if (threadIdx.x == 0) s = 0;
    __syncthreads();
    int c = 0;
    for (int i = threadIdx.x; i < 16384; i += 256) {
        unsigned short u = raw[i];
        if ((u & 0x7F80) == 0x7F80) c++;
    }
    atomicAdd(&s, c);
    __syncthreads();
    if (threadIdx.x == 0) *flag = (s > 0) ? 1 : 0;  // 1 => fp32
}

__global__ void k_init(const void* __restrict__ ue, const void* __restrict__ ie,
                       const int* __restrict__ flag,
                       float* __restrict__ ego, float* __restrict__ out) {
    int i = blockIdx.x * blockDim.x + threadIdx.x;
    if (i >= NTOT * EMB) return;
    bool isf32 = (*flag != 0);
    float v;
    if (i < N_USER * EMB) {
        v = isf32 ? ((const float*)ue)[i]
                  : __bfloat162float(((const __hip_bfloat16*)ue)[i]);
    } else {
        int j = i - N_USER * EMB;
        v = isf32 ? ((const float*)ie)[j]
                  : __bfloat162float(((const __hip_bfloat16*)ie)[j]);
    }
    ego[i] = v;
    out[i] = v * (1.0f / 3.0f);   // mean-of-3 accumulator, term 1
}

__global__ void k_initL(float* __restrict__ L) {
    int i = blockIdx.x * blockDim.x + threadIdx.x;
    if (i < EDGES * FAC) L[i] = -LOG4;   // log-softmax of all-ones logits
}

// ---- CSR build ----
__global__ void k_deg(const int* __restrict__ h, int* __restrict__ deg) {
    int e = blockIdx.x * blockDim.x + threadIdx.x;
    if (e < EDGES) atomicAdd(&deg[h[e]], 1);
}

__global__ void k_scan1(const int* __restrict__ deg, int* __restrict__ off,
                        int* __restrict__ bsum) {
    __shared__ int buf[SB];
    int tid = threadIdx.x;
    int i = blockIdx.x * SB + tid;
    int v = (i < NTOT) ? deg[i] : 0;
    buf[tid] = v;
    __syncthreads();
    for (int s = 1; s < SB; s <<= 1) {
        int t = (tid >= s) ? buf[tid - s] : 0;
        __syncthreads();
        buf[tid] += t;
        __syncthreads();
    }
    if (i < NTOT) off[i] = buf[tid] - v;
    if (tid == SB - 1) bsum[blockIdx.x] = buf[tid];
}

__global__ void k_scan2(const int* __restrict__ bsum, int* __restrict__ bbase) {
    __shared__ int b[128];
    int tid = threadIdx.x;
    int v = (tid < NBLK) ? bsum[tid] : 0;
    b[tid] = v;
    __syncthreads();
    for (int s = 1; s < 128; s <<= 1) {
        int t = (tid >= s) ? b[tid - s] : 0;
        __syncthreads();
        b[tid] += t;
        __syncthreads();
    }
    if (tid < NBLK) bbase[tid] = b[tid] - v;
}

__global__ void k_scan3(int* __restrict__ off, const int* __restrict__ bbase,
                        int* __restrict__ cur) {
    int i = blockIdx.x * blockDim.x + threadIdx.x;
    if (i < NTOT) {
        int o = off[i] + bbase[i >> 10];
        off[i] = o;
        cur[i] = o;
    }
    if (i == 0) off[NTOT] = EDGES;
}

__global__ void k_scatter(const int* __restrict__ h, const int* __restrict__ t,
                          int* __restrict__ cur,
                          int* __restrict__ tlist, int* __restrict__ hlist) {
    int e = blockIdx.x * blockDim.x + threadIdx.x;
    if (e >= EDGES) return;
    int hh = h[e];
    int pos = atomicAdd(&cur[hh], 1);
    tlist[pos] = t[e];
    hlist[pos] = hh;
}

// ---- per-layer: tnh[n] = tanh(ego[n] normalized per 16-dim factor) ----
__global__ void k_tnh(const float* __restrict__ ego, float* __restrict__ tnh) {
    int gid = blockIdx.x * blockDim.x + threadIdx.x;
    int wid = gid >> 6;
    int lane = threadIdx.x & 63;
    if (wid >= NTOT) return;
    float v = ego[wid * 64 + lane];
    float ss = v * v;
    ss += __shfl_xor(ss, 1); ss += __shfl_xor(ss, 2);
    ss += __shfl_xor(ss, 4); ss += __shfl_xor(ss, 8);
    float r = 1.0f / fmaxf(sqrtf(ss), 1e-12f);
    tnh[wid * 64 + lane] = tanhf(v * r);
}

// ---- pass 0 dinv: softmax(ones)=0.25 -> dval = 0.25*deg ----
__global__ void k_dinv0(const int* __restrict__ deg, float* __restrict__ dvinv) {
    int i = blockIdx.x * blockDim.x + threadIdx.x;
    if (i >= NTOT * FAC) return;
    float dval = 0.25f * (float)deg[i >> 2];
    dvinv[i] = rsqrtf(fmaxf(dval, 1e-8f));
}

// ---- dval[n,f] = sum_j exp(L[j,f]); quad of lanes per node ----
__global__ void k_dv(const float* __restrict__ L, const int* __restrict__ off,
                     float* __restrict__ dvinv) {
    int tid = blockIdx.x * blockDim.x + threadIdx.x;
    if (tid >= NTOT * FAC) return;
    int n = tid >> 2, f = tid & 3;
    int beg = off[n], end = off[n + 1];
    float s = 0.f;
    for (int j = beg; j < end; ++j) s += __expf(L[j * 4 + f]);
    dvinv[tid] = rsqrtf(fmaxf(s, 1e-8f));
}

// ---- message passing, gather form, unrolled x4 for MLP ----
__global__ void k_mp(const float* __restrict__ ego, const float* __restrict__ L,
                     const float* __restrict__ dvinv, const int* __restrict__ off,
                     const int* __restrict__ tlist,
                     float* __restrict__ fac, float* __restrict__ rhn,
                     float* __restrict__ out, int writeRhn, int addOut) {
    int gid = blockIdx.x * blockDim.x + threadIdx.x;
    int wid = gid >> 6;
    int lane = threadIdx.x & 63;
    if (wid >= NTOT) return;
    int f = lane >> 4;
    int beg = off[wid], end = off[wid + 1];
    float dvh = dvinv[wid * 4 + f];
    float acc = 0.f;
    int j = beg;
    for (; j + 4 <= end; j += 4) {
        int t0 = tlist[j], t1 = tlist[j + 1], t2 = tlist[j + 2], t3 = tlist[j + 3];
        float l0 = L[(j + 0) * 4 + f], l1 = L[(j + 1) * 4 + f],
              l2 = L[(j + 2) * 4 + f], l3 = L[(j + 3) * 4 + f];
        float d0 = dvinv[t0 * 4 + f], d1 = dvinv[t1 * 4 + f],
              d2 = dvinv[t2 * 4 + f], d3 = dvinv[t3 * 4 + f];
        float g0 = ego[t0 * 64 + lane], g1 = ego[t1 * 64 + lane],
              g2 = ego[t2 * 64 + lane], g3 = ego[t3 * 64 + lane];
        acc += __expf(l0) * d0 * g0 + __expf(l1) * d1 * g1
             + __expf(l2) * d2 * g2 + __expf(l3) * d3 * g3;
    }
    for (; j < end; ++j) {
        int t = tlist[j];
        acc += __expf(L[j * 4 + f]) * dvinv[t * 4 + f] * ego[t * 64 + lane];
    }
    acc *= dvh;
    fac[wid * 64 + lane] = acc;
    if (addOut) out[wid * 64 + lane] += acc * (1.0f / 3.0f);
    if (writeRhn) {
        float ss = acc * acc;
        ss += __shfl_xor(ss, 1); ss += __shfl_xor(ss, 2);
        ss += __shfl_xor(ss, 4); ss += __shfl_xor(ss, 8);
        if ((lane & 15) == 0) rhn[wid * 4 + f] = 1.0f / fmaxf(sqrtf(ss), 1e-12f);
    }
}

// ---- routing update, edge-parallel: thread = CSR position j, all 4 factors ----
__global__ void k_upd(const float* __restrict__ fac, const float* __restrict__ tnh,
                      const float* __restrict__ rhn,
                      const int* __restrict__ hlist, const int* __restrict__ tlist,
                      float* __restrict__ L) {
    int j = blockIdx.x * blockDim.x + threadIdx.x;
    if (j >= EDGES) return;
    int h = hlist[j], t = tlist[j];
    const float4* fp = (const float4*)(fac + h * 64);
    const float4* tp = (const float4*)(tnh + t * 64);
    float d0 = 0.f, d1 = 0.f, d2 = 0.f, d3 = 0.f;
#pragma unroll
    for (int i = 0; i < 4; ++i) {
        float4 a = fp[0 * 4 + i], b = tp[0 * 4 + i];
        d0 += a.x * b.x + a.y * b.y + a.z * b.z + a.w * b.w;
    }
#pragma unroll
    for (int i = 0; i < 4; ++i) {
        float4 a = fp[1 * 4 + i], b = tp[1 * 4 + i];
        d1 += a.x * b.x + a.y * b.y + a.z * b.z + a.w * b.w;
    }
#pragma unroll
    for (int i = 0; i < 4; ++i) {
        float4 a = fp[2 * 4 + i], b = tp[2 * 4 + i];
        d2 += a.x * b.x + a.y * b.y + a.z * b.z + a.w * b.w;
    }
#pragma unroll
    for (int i = 0; i < 4; ++i) {
        float4 a = fp[3 * 4 + i], b = tp[3 * 4 + i];
        d3 += a.x * b.x + a.y * b.y + a.z * b.z + a.w * b.w;
    }
    float4 rh = ((const float4*)rhn)[h];
    float4 l0 = ((const float4*)L)[j];
    float y0 = l0.x + rh.x * d0, y1 = l0.y + rh.y * d1,
          y2 = l0.z + rh.z * d2, y3 = l0.w + rh.w * d3;
    float m = fmaxf(fmaxf(y0, y1), fmaxf(y2, y3));
    float e0 = __expf(y0 - m), e1 = __expf(y1 - m),
          e2 = __expf(y2 - m), e3 = __expf(y3 - m);
    float lse = m + __logf(e0 + e1 + e2 + e3);
    ((float4*)L)[j] = make_float4(y0 - lse, y1 - lse, y2 - lse, y3 - lse);
}

extern "C" void kernel_launch(void* const* d_in, const int* in_sizes, int n_in,
                              void* d_out, int out_size, void* d_ws, size_t ws_size,
                              hipStream_t stream) {
    const void* ue = d_in[0];
    const void* ie = d_in[1];
    const int* hl = (const int*)d_in[2];
    const int* tl = (const int*)d_in[3];
    float* out = (float*)d_out;

    float* ws    = (float*)d_ws;
    float* ego   = ws;
    float* fac   = ws + 5120000;
    float* tnh   = ws + 10240000;
    float* L     = ws + 15360000;
    float* dvinv = ws + 19360000;
    float* rhn   = ws + 19680000;
    int*   flag  = (int*)(ws + 20000000);
    int*   ib    = (int*)(ws + 20000016);
    int*   deg   = ib;                   // 80000
    int*   off   = ib + 80000;           // 80001
    int*   cur   = ib + 160001;          // 80000
    int*   tlist = ib + 240001;          // 1,000,000
    int*   hlist = ib + 1240001;         // 1,000,000
    int*   bsum  = ib + 2240001;         // 128
    int*   bbase = ib + 2240129;         // 128

    k_detect<<<1, 256, 0, stream>>>((const unsigned short*)ue, flag);
    k_init<<<20000, 256, 0, stream>>>(ue, ie, flag, ego, out);
    k_initL<<<15625, 256, 0, stream>>>(L);

    hipMemsetAsync(deg, 0, NTOT * sizeof(int), stream);
    k_deg<<<3907, 256, 0, stream>>>(hl, deg);
    k_scan1<<<NBLK, SB, 0, stream>>>(deg, off, bsum);
    k_scan2<<<1, 128, 0, stream>>>(bsum, bbase);
    k_scan3<<<313, 256, 0, stream>>>(off, bbase, cur);
    k_scatter<<<3907, 256, 0, stream>>>(hl, tl, cur, tlist, hlist);

    // layer 0
    k_tnh<<<20000, 256, 0, stream>>>(ego, tnh);
    k_dinv0<<<1250, 256, 0, stream>>>(deg, dvinv);
    k_mp<<<20000, 256, 0, stream>>>(ego, L, dvinv, off, tlist, fac, rhn, out, 1, 0); // p0
    k_upd<<<3907, 256, 0, stream>>>(fac, tnh, rhn, hlist, tlist, L);
    k_dv<<<1250, 256, 0, stream>>>(L, off, dvinv);
    k_mp<<<20000, 256, 0, stream>>>(ego, L, dvinv, off, tlist, fac, rhn, out, 1, 1); // p1
    k_upd<<<3907, 256, 0, stream>>>(fac, tnh, rhn, hlist, tlist, L);
    k_dv<<<1250, 256, 0, stream>>>(L, off, dvinv);
    // layer 1
    { float* tmp = ego; ego = fac; fac = tmp; }
    k_tnh<<<20000, 256, 0, stream>>>(ego, tnh);
    k_mp<<<20000, 256, 0, stream>>>(ego, L, dvinv, off, tlist, fac, rhn, out, 1, 0); // p2
    k_upd<<<3907, 256, 0, stream>>>(fac, tnh, rhn, hlist, tlist, L);
    k_dv<<<1250, 256, 0, stream>>>(L, off, dvinv);
    k_mp<<<20000, 256, 0, stream>>>(ego, L, dvinv, off, tlist, fac, rhn, out, 0, 1); // p3
}